// Round 1
// baseline (397.055 us; speedup 1.0000x reference)
//
#include <hip/hip_runtime.h>
#include <hip/hip_bf16.h>
#include <stdint.h>

#define NN 10000
#define NF 256
#define NSTEPS 313   // ceil(10000/32)

typedef float f32x4 __attribute__((ext_vector_type(4)));
typedef __bf16 bf16x8 __attribute__((ext_vector_type(8)));
typedef unsigned short u16;

__device__ __forceinline__ u16 f2bf(float f) {
    __bf16 h = (__bf16)f;
    return __builtin_bit_cast(u16, h);
}
__device__ __forceinline__ float bf2f(u16 b) {
    return (float)__builtin_bit_cast(__bf16, b);
}

// ---------------- kernel 1: deg -> dinv ----------------
__global__ __launch_bounds__(256) void k_deg(const float* __restrict__ adj,
                                             float* __restrict__ dinv) {
    const int row = blockIdx.x;
    const f32x4* rp = reinterpret_cast<const f32x4*>(adj + (size_t)row * NN);
    float s = 0.f;
    for (int j = threadIdx.x; j < NN / 4; j += 256) {
        f32x4 v = rp[j];
        s += (v[0] + v[1]) + (v[2] + v[3]);
    }
#pragma unroll
    for (int off = 32; off > 0; off >>= 1) s += __shfl_down(s, off, 64);
    __shared__ float red[4];
    const int lane = threadIdx.x & 63, w = threadIdx.x >> 6;
    if (lane == 0) red[w] = s;
    __syncthreads();
    if (threadIdx.x == 0) {
        float deg = (red[0] + red[1]) + (red[2] + red[3]);
        dinv[row] = deg > 0.f ? 1.0f / sqrtf(deg) : 0.0f;
    }
}

// ---------------- kernel 2: S' = dinv * (features @ W), store S' and S'^T (bf16) ----------------
// grid (157, 4): 64-row x 64-col tiles. 256 threads = 16 rowgrp x 16 colgrp, 4x4 acc each.
__global__ __launch_bounds__(256) void k_support(const float* __restrict__ feat,
                                                 const float* __restrict__ W,
                                                 const float* __restrict__ dinv,
                                                 u16* __restrict__ SP,
                                                 u16* __restrict__ SPT) {
    const int j0 = blockIdx.x * 64;
    const int c0 = blockIdx.y * 64;
    __shared__ float flds[128][64];   // [f][r] transposed, 32 KB
    const int t = threadIdx.x;
    const int rg = t & 15, cg = t >> 4;
    const int sr = t >> 2, sf = (t & 3) * 32;
    float acc[4][4] = {};

    for (int half = 0; half < 2; ++half) {
        __syncthreads();
        const int gj = j0 + sr;
#pragma unroll
        for (int i = 0; i < 8; ++i) {
            f32x4 v = {};
            if (gj < NN)
                v = *reinterpret_cast<const f32x4*>(&feat[(size_t)gj * NF + half * 128 + sf + i * 4]);
#pragma unroll
            for (int u = 0; u < 4; ++u) flds[sf + i * 4 + u][sr] = v[u];
        }
        __syncthreads();
#pragma unroll 4
        for (int f = 0; f < 128; ++f) {
            f32x4 fv = *reinterpret_cast<const f32x4*>(&flds[f][rg * 4]);
            f32x4 wv = *reinterpret_cast<const f32x4*>(&W[(size_t)(half * 128 + f) * NF + c0 + cg * 4]);
#pragma unroll
            for (int r = 0; r < 4; ++r)
#pragma unroll
                for (int c = 0; c < 4; ++c)
                    acc[r][c] = fmaf(fv[r], wv[c], acc[r][c]);
        }
    }

    const int jb = j0 + rg * 4;
    if (jb < NN) {   // 10000 % 4 == 0 -> 4-row chunks are all-or-nothing valid
        u16 bits[4][4];
#pragma unroll
        for (int r = 0; r < 4; ++r) {
            const float dv = dinv[jb + r];
#pragma unroll
            for (int c = 0; c < 4; ++c) bits[r][c] = f2bf(acc[r][c] * dv);
        }
#pragma unroll
        for (int r = 0; r < 4; ++r) {
            ushort4 v; v.x = bits[r][0]; v.y = bits[r][1]; v.z = bits[r][2]; v.w = bits[r][3];
            *reinterpret_cast<ushort4*>(&SP[(size_t)(jb + r) * NF + c0 + cg * 4]) = v;
        }
#pragma unroll
        for (int c = 0; c < 4; ++c) {
            ushort4 v; v.x = bits[0][c]; v.y = bits[1][c]; v.z = bits[2][c]; v.w = bits[3][c];
            *reinterpret_cast<ushort4*>(&SPT[(size_t)(c0 + cg * 4 + c) * NN + jb]) = v;
        }
    }
}

// ---------------- kernel 3: P[ks] = adj(m-tile, k-chunk) @ S'  (bf16 MFMA) ----------------
// grid (157, KSPLIT). 256 threads = 4 waves; wave w covers all 64 M-rows x 64 N-cols.
__global__ __launch_bounds__(256) void k_gemm(const float* __restrict__ adj,
                                              const u16* __restrict__ SPT,
                                              float* __restrict__ P) {
    const int mt = blockIdx.x, ks = blockIdx.y, nsp = gridDim.y;
    const int m0 = mt * 64;
    const int base = NSTEPS / nsp, extra = NSTEPS % nsp;
    const int s0 = ks * base + (ks < extra ? ks : extra);
    const int s1 = s0 + base + (ks < extra ? 1 : 0);

    __shared__ u16 Alds[64][40];    // 80 B row stride (padded: conflict-free b128)
    __shared__ u16 Blds[NF][40];    // [n][k] 80 B stride

    const int t = threadIdx.x;
    const int ar = t >> 2, akq = t & 3;
    const int gi = m0 + ar;
    const u16* brow = SPT + (size_t)t * NN;

    const int lane = t & 63, wid = t >> 6;
    const int nb = wid * 64;
    const int lrow = lane & 15, lk = lane >> 4;

    f32x4 acc[4][4] = {};

    for (int s = s0; s < s1; ++s) {
        const int k0 = s * 32;
        // stage A: 64x32 fp32 -> bf16 (8 floats / thread)
        const int ka = k0 + akq * 8;
        f32x4 a0 = {}, a1 = {};
        if (gi < NN && ka < NN) {
            const float* ap = adj + (size_t)gi * NN + ka;
            a0 = *reinterpret_cast<const f32x4*>(ap);
            a1 = *reinterpret_cast<const f32x4*>(ap + 4);
        }
        bf16x8 apk;
        apk[0] = (__bf16)a0[0]; apk[1] = (__bf16)a0[1];
        apk[2] = (__bf16)a0[2]; apk[3] = (__bf16)a0[3];
        apk[4] = (__bf16)a1[0]; apk[5] = (__bf16)a1[1];
        apk[6] = (__bf16)a1[2]; apk[7] = (__bf16)a1[3];
        // stage B: thread t copies row n=t of S'^T (32 k-values)
        uint4 bv[4];
#pragma unroll
        for (int c = 0; c < 4; ++c) {
            const int kb = k0 + c * 8;
            if (kb < NN) bv[c] = *reinterpret_cast<const uint4*>(brow + kb);
            else         bv[c] = make_uint4(0, 0, 0, 0);
        }
        __syncthreads();   // previous iteration's readers done
        *reinterpret_cast<bf16x8*>(&Alds[ar][akq * 8]) = apk;
#pragma unroll
        for (int c = 0; c < 4; ++c)
            *reinterpret_cast<uint4*>(&Blds[t][c * 8]) = bv[c];
        __syncthreads();
        // compute: 4 m-frags x 4 n-frags
        bf16x8 af[4], bfr[4];
#pragma unroll
        for (int i = 0; i < 4; ++i)
            af[i] = *reinterpret_cast<const bf16x8*>(&Alds[i * 16 + lrow][lk * 8]);
#pragma unroll
        for (int i = 0; i < 4; ++i)
            bfr[i] = *reinterpret_cast<const bf16x8*>(&Blds[nb + i * 16 + lrow][lk * 8]);
#pragma unroll
        for (int i = 0; i < 4; ++i)
#pragma unroll
            for (int j = 0; j < 4; ++j)
                acc[i][j] = __builtin_amdgcn_mfma_f32_16x16x32_bf16(af[i], bfr[j], acc[i][j], 0, 0, 0);
    }

    float* Pp = P + (size_t)ks * ((size_t)NN * NF);
#pragma unroll
    for (int i = 0; i < 4; ++i) {
        const int row_b = m0 + i * 16 + lk * 4;   // C/D: col=lane&15, row=(lane>>4)*4+reg
#pragma unroll
        for (int r = 0; r < 4; ++r) {
            const int row = row_b + r;
            if (row < NN) {
#pragma unroll
                for (int j = 0; j < 4; ++j)
                    Pp[(size_t)row * NF + nb + j * 16 + lrow] = acc[i][j][r];
            }
        }
    }
}

// ---------------- kernel 4: out = relu(dinv*(sum P) + 2*dinv*S' + b) ----------------
__global__ __launch_bounds__(256) void k_out(const float* __restrict__ P, int nsp,
                                             const u16* __restrict__ SP,
                                             const float* __restrict__ dinv,
                                             const float* __restrict__ bias,
                                             float* __restrict__ out) {
    const size_t e0 = ((size_t)blockIdx.x * 256 + threadIdx.x) * 4;
    const int i = (int)(e0 >> 8);
    const int k = (int)(e0 & 255);
    f32x4 sum = {};
    for (int s = 0; s < nsp; ++s)
        sum += *reinterpret_cast<const f32x4*>(&P[(size_t)s * NN * NF + e0]);
    const float dv = dinv[i];
    f32x4 bv = *reinterpret_cast<const f32x4*>(&bias[k]);
    ushort4 sp = *reinterpret_cast<const ushort4*>(&SP[e0]);
    f32x4 spf;
    spf[0] = bf2f(sp.x); spf[1] = bf2f(sp.y); spf[2] = bf2f(sp.z); spf[3] = bf2f(sp.w);
    f32x4 o;
#pragma unroll
    for (int c = 0; c < 4; ++c) {
        float v = dv * sum[c] + 2.f * dv * spf[c] + bv[c];
        o[c] = fmaxf(v, 0.f);
    }
    *reinterpret_cast<f32x4*>(&out[e0]) = o;
}

extern "C" void kernel_launch(void* const* d_in, const int* in_sizes, int n_in,
                              void* d_out, int out_size, void* d_ws, size_t ws_size,
                              hipStream_t stream) {
    const float* adj  = (const float*)d_in[0];
    const float* feat = (const float*)d_in[1];
    const float* W    = (const float*)d_in[2];
    const float* bias = (const float*)d_in[3];
    // d_in[4] (a) is mathematically unused: softmax over a size-1 axis == 1.

    char* ws = (char*)d_ws;
    const size_t SPT_OFF  = 0;                       // 256*10000*2 = 5,120,000
    const size_t SP_OFF   = 5120000;                 // + 5,120,000
    const size_t DINV_OFF = 10240000;                // + 40,000
    const size_t P_OFF    = 10280000;                // + nsp * 10,240,000
    u16*   SPT  = (u16*)(ws + SPT_OFF);
    u16*   SP   = (u16*)(ws + SP_OFF);
    float* dinv = (float*)(ws + DINV_OFF);
    float* P    = (float*)(ws + P_OFF);

    int nsp = (int)((ws_size - P_OFF) / ((size_t)NN * NF * sizeof(float)));
    if (nsp > 4) nsp = 4;
    if (nsp < 1) nsp = 1;

    k_deg<<<NN, 256, 0, stream>>>(adj, dinv);
    k_support<<<dim3(157, 4), 256, 0, stream>>>(feat, W, dinv, SP, SPT);
    k_gemm<<<dim3(157, (unsigned)nsp), 256, 0, stream>>>(adj, SPT, P);
    k_out<<<2500, 256, 0, stream>>>(P, nsp, SP, dinv, bias, (float*)d_out);
}

// Round 2
// 299.392 us; speedup vs baseline: 1.3262x; 1.3262x over previous
//
#include <hip/hip_runtime.h>
#include <hip/hip_bf16.h>
#include <stdint.h>

#define NN 10000
#define NF 256
#define NSTEPS 313   // ceil(10000/32)

typedef float f32x4 __attribute__((ext_vector_type(4)));
typedef __bf16 bf16x8 __attribute__((ext_vector_type(8)));
typedef unsigned short u16;

__device__ __forceinline__ u16 f2bf(float f) {
    __bf16 h = (__bf16)f;
    return __builtin_bit_cast(u16, h);
}
__device__ __forceinline__ float bf2f(u16 b) {
    return (float)__builtin_bit_cast(__bf16, b);
}

// ---------------- kernel 1: deg -> dinv ----------------
__global__ __launch_bounds__(256) void k_deg(const float* __restrict__ adj,
                                             float* __restrict__ dinv) {
    const int row = blockIdx.x;
    const f32x4* rp = reinterpret_cast<const f32x4*>(adj + (size_t)row * NN);
    float s = 0.f;
    for (int j = threadIdx.x; j < NN / 4; j += 256) {
        f32x4 v = rp[j];
        s += (v[0] + v[1]) + (v[2] + v[3]);
    }
#pragma unroll
    for (int off = 32; off > 0; off >>= 1) s += __shfl_down(s, off, 64);
    __shared__ float red[4];
    const int lane = threadIdx.x & 63, w = threadIdx.x >> 6;
    if (lane == 0) red[w] = s;
    __syncthreads();
    if (threadIdx.x == 0) {
        float deg = (red[0] + red[1]) + (red[2] + red[3]);
        dinv[row] = deg > 0.f ? 1.0f / sqrtf(deg) : 0.0f;
    }
}

// ---------------- kernel 2: S' = dinv * (features @ W), store S' and S'^T (bf16) ----------------
__global__ __launch_bounds__(256) void k_support(const float* __restrict__ feat,
                                                 const float* __restrict__ W,
                                                 const float* __restrict__ dinv,
                                                 u16* __restrict__ SP,
                                                 u16* __restrict__ SPT) {
    const int j0 = blockIdx.x * 64;
    const int c0 = blockIdx.y * 64;
    __shared__ float flds[128][64];   // [f][r] transposed, 32 KB
    const int t = threadIdx.x;
    const int rg = t & 15, cg = t >> 4;
    const int sr = t >> 2, sf = (t & 3) * 32;
    float acc[4][4] = {};

    for (int half = 0; half < 2; ++half) {
        __syncthreads();
        const int gj = j0 + sr;
#pragma unroll
        for (int i = 0; i < 8; ++i) {
            f32x4 v = {};
            if (gj < NN)
                v = *reinterpret_cast<const f32x4*>(&feat[(size_t)gj * NF + half * 128 + sf + i * 4]);
#pragma unroll
            for (int u = 0; u < 4; ++u) flds[sf + i * 4 + u][sr] = v[u];
        }
        __syncthreads();
#pragma unroll 4
        for (int f = 0; f < 128; ++f) {
            f32x4 fv = *reinterpret_cast<const f32x4*>(&flds[f][rg * 4]);
            f32x4 wv = *reinterpret_cast<const f32x4*>(&W[(size_t)(half * 128 + f) * NF + c0 + cg * 4]);
#pragma unroll
            for (int r = 0; r < 4; ++r)
#pragma unroll
                for (int c = 0; c < 4; ++c)
                    acc[r][c] = fmaf(fv[r], wv[c], acc[r][c]);
        }
    }

    const int jb = j0 + rg * 4;
    if (jb < NN) {
        u16 bits[4][4];
#pragma unroll
        for (int r = 0; r < 4; ++r) {
            const float dv = dinv[jb + r];
#pragma unroll
            for (int c = 0; c < 4; ++c) bits[r][c] = f2bf(acc[r][c] * dv);
        }
#pragma unroll
        for (int r = 0; r < 4; ++r) {
            ushort4 v; v.x = bits[r][0]; v.y = bits[r][1]; v.z = bits[r][2]; v.w = bits[r][3];
            *reinterpret_cast<ushort4*>(&SP[(size_t)(jb + r) * NF + c0 + cg * 4]) = v;
        }
#pragma unroll
        for (int c = 0; c < 4; ++c) {
            ushort4 v; v.x = bits[0][c]; v.y = bits[1][c]; v.z = bits[2][c]; v.w = bits[3][c];
            *reinterpret_cast<ushort4*>(&SPT[(size_t)(c0 + cg * 4 + c) * NN + jb]) = v;
        }
    }
}

// ---------------- kernel 3: P[ks] = adj(m-tile, k-chunk) @ S'  (bf16 MFMA) ----------------
// Block = 4 waves, M-tile 64, each wave owns 64 output cols (full N=256 per block).
// A: global_load_lds (16B, pre-swizzled source so ds_read_b128 is ~2-way conflict-free).
// B: per-lane direct global loads from L2-resident SPT. 1-deep prefetch, 1 sync/step.
__global__ __launch_bounds__(256) void k_gemm(const float* __restrict__ adj,
                                              const u16* __restrict__ SPT,
                                              float* __restrict__ P) {
    const int mt = blockIdx.x, ks = blockIdx.y, nsp = gridDim.y;
    const int m0 = mt * 64;
    const int base = NSTEPS / nsp, extra = NSTEPS % nsp;
    const int s0 = ks * base + (ks < extra ? ks : extra);
    const int s1 = s0 + base + (ks < extra ? 1 : 0);

    __shared__ float Albuf[2][2048];   // 2 x 8KB: 64 rows x 32 fp32, chunk-swizzled

    const int t = threadIdx.x;
    const int lane = t & 63, wid = t >> 6;
    const int nb = wid * 64;
    const int lrow = lane & 15, lk = lane >> 4;

    const u16* bp0 = SPT + (size_t)(nb + lrow) * NN + lk * 8;
    const u16* bp1 = bp0 + (size_t)16 * NN;
    const u16* bp2 = bp0 + (size_t)32 * NN;
    const u16* bp3 = bp0 + (size_t)48 * NN;

    f32x4 acc[4][4] = {};
    uint4 bc0, bc1, bc2, bc3, bn0, bn1, bn2, bn3;

    auto stage = [&](int bufidx, int k0v) {
#pragma unroll
        for (int is = 0; is < 2; ++is) {
            const int r = (t >> 3) + is * 32;
            const int g = (t & 7) ^ (r & 7);     // which global 16B chunk this slot holds
            const int row = m0 + r;
            const int kc = k0v + g * 4;
            const float* src = (row < NN && kc < NN) ? (adj + (size_t)row * NN + kc) : adj;
            __builtin_amdgcn_global_load_lds(
                (const __attribute__((address_space(1))) void*)src,
                (__attribute__((address_space(3))) void*)&Albuf[bufidx][t * 4 + is * 1024],
                16, 0, 0);
        }
    };
    auto loadB = [&](int k0v, uint4& b0, uint4& b1, uint4& b2, uint4& b3) {
        const bool kv = (k0v + lk * 8) < NN;
        b0 = b1 = b2 = b3 = make_uint4(0, 0, 0, 0);
        if (kv) {
            b0 = *reinterpret_cast<const uint4*>(bp0 + k0v);
            b1 = *reinterpret_cast<const uint4*>(bp1 + k0v);
            b2 = *reinterpret_cast<const uint4*>(bp2 + k0v);
            b3 = *reinterpret_cast<const uint4*>(bp3 + k0v);
        }
    };

    stage(0, s0 * 32);
    loadB(s0 * 32, bc0, bc1, bc2, bc3);
    __syncthreads();

    int cb = 0;
    for (int s = s0; s < s1; ++s) {
        const int k0 = s * 32;
        const bool hn = (s + 1 < s1);
        if (hn) {
            stage(cb ^ 1, k0 + 32);
            loadB(k0 + 32, bn0, bn1, bn2, bn3);
        }
        // A fragments from swizzled LDS, fp32 -> bf16
        const bool kvA = (k0 + lk * 8) < NN;
        bf16x8 af[4];
        const bf16x8 zz = (bf16x8)(__bf16)0.0f;
#pragma unroll
        for (int i = 0; i < 4; ++i) {
            const int row = i * 16 + lrow;
            const int sl0 = (lk * 2) ^ (row & 7);
            const int sl1 = (lk * 2 + 1) ^ (row & 7);
            f32x4 x0 = *reinterpret_cast<const f32x4*>(&Albuf[cb][row * 32 + sl0 * 4]);
            f32x4 x1 = *reinterpret_cast<const f32x4*>(&Albuf[cb][row * 32 + sl1 * 4]);
            bf16x8 a;
            a[0] = (__bf16)x0[0]; a[1] = (__bf16)x0[1]; a[2] = (__bf16)x0[2]; a[3] = (__bf16)x0[3];
            a[4] = (__bf16)x1[0]; a[5] = (__bf16)x1[1]; a[6] = (__bf16)x1[2]; a[7] = (__bf16)x1[3];
            af[i] = kvA ? a : zz;
        }
        const bf16x8 bf0 = *reinterpret_cast<const bf16x8*>(&bc0);
        const bf16x8 bf1 = *reinterpret_cast<const bf16x8*>(&bc1);
        const bf16x8 bf2 = *reinterpret_cast<const bf16x8*>(&bc2);
        const bf16x8 bf3 = *reinterpret_cast<const bf16x8*>(&bc3);
#pragma unroll
        for (int i = 0; i < 4; ++i) {
            acc[i][0] = __builtin_amdgcn_mfma_f32_16x16x32_bf16(af[i], bf0, acc[i][0], 0, 0, 0);
            acc[i][1] = __builtin_amdgcn_mfma_f32_16x16x32_bf16(af[i], bf1, acc[i][1], 0, 0, 0);
            acc[i][2] = __builtin_amdgcn_mfma_f32_16x16x32_bf16(af[i], bf2, acc[i][2], 0, 0, 0);
            acc[i][3] = __builtin_amdgcn_mfma_f32_16x16x32_bf16(af[i], bf3, acc[i][3], 0, 0, 0);
        }
        __syncthreads();   // drains the prefetch DMA + makes buf[cb^1] visible
        bc0 = bn0; bc1 = bn1; bc2 = bn2; bc3 = bn3;
        cb ^= 1;
    }

    float* Pp = P + (size_t)ks * ((size_t)NN * NF);
#pragma unroll
    for (int i = 0; i < 4; ++i) {
        const int row_b = m0 + i * 16 + lk * 4;   // C/D: col=lane&15, row=(lane>>4)*4+reg
#pragma unroll
        for (int r = 0; r < 4; ++r) {
            const int row = row_b + r;
            if (row < NN) {
#pragma unroll
                for (int j = 0; j < 4; ++j)
                    Pp[(size_t)row * NF + nb + j * 16 + lrow] = acc[i][j][r];
            }
        }
    }
}

// ---------------- kernel 4: out = relu(dinv*(sum P) + 2*dinv*S' + b) ----------------
__global__ __launch_bounds__(256) void k_out(const float* __restrict__ P, int nsp,
                                             const u16* __restrict__ SP,
                                             const float* __restrict__ dinv,
                                             const float* __restrict__ bias,
                                             float* __restrict__ out) {
    const size_t e0 = ((size_t)blockIdx.x * 256 + threadIdx.x) * 4;
    const int i = (int)(e0 >> 8);
    const int k = (int)(e0 & 255);
    f32x4 sum = {};
    for (int s = 0; s < nsp; ++s)
        sum += *reinterpret_cast<const f32x4*>(&P[(size_t)s * NN * NF + e0]);
    const float dv = dinv[i];
    f32x4 bv = *reinterpret_cast<const f32x4*>(&bias[k]);
    ushort4 sp = *reinterpret_cast<const ushort4*>(&SP[e0]);
    f32x4 spf;
    spf[0] = bf2f(sp.x); spf[1] = bf2f(sp.y); spf[2] = bf2f(sp.z); spf[3] = bf2f(sp.w);
    f32x4 o;
#pragma unroll
    for (int c = 0; c < 4; ++c) {
        float v = dv * sum[c] + 2.f * dv * spf[c] + bv[c];
        o[c] = fmaxf(v, 0.f);
    }
    *reinterpret_cast<f32x4*>(&out[e0]) = o;
}

extern "C" void kernel_launch(void* const* d_in, const int* in_sizes, int n_in,
                              void* d_out, int out_size, void* d_ws, size_t ws_size,
                              hipStream_t stream) {
    const float* adj  = (const float*)d_in[0];
    const float* feat = (const float*)d_in[1];
    const float* W    = (const float*)d_in[2];
    const float* bias = (const float*)d_in[3];
    // d_in[4] (a) is mathematically unused: softmax over a size-1 axis == 1.

    char* ws = (char*)d_ws;
    const size_t SPT_OFF  = 0;                       // 256*10000*2 = 5,120,000
    const size_t SP_OFF   = 5120000;                 // + 5,120,000
    const size_t DINV_OFF = 10240000;                // + 40,000
    const size_t P_OFF    = 10280000;                // + nsp * 10,240,000
    u16*   SPT  = (u16*)(ws + SPT_OFF);
    u16*   SP   = (u16*)(ws + SP_OFF);
    float* dinv = (float*)(ws + DINV_OFF);
    float* P    = (float*)(ws + P_OFF);

    int nsp = (int)((ws_size - P_OFF) / ((size_t)NN * NF * sizeof(float)));
    if (nsp > 8) nsp = 8;
    if (nsp < 1) nsp = 1;

    k_deg<<<NN, 256, 0, stream>>>(adj, dinv);
    k_support<<<dim3(157, 4), 256, 0, stream>>>(feat, W, dinv, SP, SPT);
    k_gemm<<<dim3(157, (unsigned)nsp), 256, 0, stream>>>(adj, SPT, P);
    k_out<<<2500, 256, 0, stream>>>(P, nsp, SP, dinv, bias, (float*)d_out);
}